// Round 5
// baseline (195.691 us; speedup 1.0000x reference)
//
#include <hip/hip_runtime.h>
#include <math.h>

#define NROWS 8192
#define HALF  4096
#define EMB   2048
#define DIM   256
#define INV_T 10.0f

typedef __bf16 bf16x8v __attribute__((ext_vector_type(8)));
typedef __bf16 bf16x4v __attribute__((ext_vector_type(4)));
typedef float  f32x4   __attribute__((ext_vector_type(4)));

__device__ __forceinline__ void gld_lds16(const void* g, void* l) {
    __builtin_amdgcn_global_load_lds((const __attribute__((address_space(1))) void*)g,
                                     (__attribute__((address_space(3))) void*)l,
                                     16, 0, 0);
}

// ---------- K0: W [2048][256] f32 -> Wt [256][2048] bf16, coalesced tile transpose ----------
__global__ __launch_bounds__(256) void wt_kernel(const float* __restrict__ W,
                                                 __bf16* __restrict__ Wt) {
    __shared__ __bf16 t[64][72];
    const int n0 = blockIdx.x * 64;
    const int k0 = blockIdx.y * 64;
    const int tid = threadIdx.x;
    const int c = tid & 63;
    const int rr = tid >> 6;
#pragma unroll
    for (int it = 0; it < 16; it++) {
        int k = it * 4 + rr;
        t[k][c] = (__bf16)W[(size_t)(k0 + k) * DIM + n0 + c];
    }
    __syncthreads();
#pragma unroll
    for (int it = 0; it < 16; it++) {
        int n = it * 4 + rr;
        Wt[(size_t)(n0 + n) * EMB + k0 + c] = t[c][n];
    }
}

// ---------- K1: fused GEMM + bias + L2-normalize, emit bf16 X ----------
// v5: BARRIER-FREE. 256 blocks x 256 thr (4 waves); block = 32 rows x 256 cols;
// wave = 32r x 64c, acc 2x4 fragments. A and B load STRAIGHT from global into
// MFMA fragments (fragment layout row/col=l15, k=quad*8 -> 16B contiguous per
// lane). No LDS staging, no loop barriers, no lockstep: each wave is an
// independent deep load pipeline (counted vmcnt by compiler). B (Wt, 1 MB) is
// L2-resident; A's 4x block re-read hits L1/L2. K-order identical to v4 ->
// bitwise-same accumulation.
#define FR 32

__global__ __launch_bounds__(256, 2) void gemm_norm_fused(
    const float* __restrict__ A,      // [8192][2048] f32
    const __bf16* __restrict__ Wt,    // [256][2048] bf16
    const float* __restrict__ bias,   // [256] f32
    __bf16* __restrict__ outb)        // [8192][256] bf16 normalized
{
    __shared__ float red[FR][4];
    __shared__ float inv_sh[FR];

    const int tid  = threadIdx.x;
    const int wave = tid >> 6, lane = tid & 63;
    const int quad = lane >> 4, l15 = lane & 15;
    const int rowBase = blockIdx.x * FR;
    const int colBase = wave * 64;

    f32x4 acc[2][4];
    const f32x4 zero = {0.f, 0.f, 0.f, 0.f};
#pragma unroll
    for (int m = 0; m < 2; m++)
#pragma unroll
        for (int n = 0; n < 4; n++) acc[m][n] = zero;

    float bv[4];
#pragma unroll
    for (int n = 0; n < 4; n++) bv[n] = bias[colBase + n * 16 + l15];

    // per-lane fragment base pointers
    const float* aB0 = A + (size_t)(rowBase + l15) * EMB + quad * 8;
    const float* aB1 = aB0 + (size_t)16 * EMB;
    const __bf16* bB0 = Wt + (size_t)(colBase + l15) * EMB + quad * 8;
    const __bf16* bB1 = bB0 + (size_t)16 * EMB;
    const __bf16* bB2 = bB0 + (size_t)32 * EMB;
    const __bf16* bB3 = bB0 + (size_t)48 * EMB;

#pragma unroll 4
    for (int k = 0; k < EMB; k += 32) {
        f32x4 a0lo = *(const f32x4*)(aB0 + k);
        f32x4 a0hi = *(const f32x4*)(aB0 + k + 4);
        f32x4 a1lo = *(const f32x4*)(aB1 + k);
        f32x4 a1hi = *(const f32x4*)(aB1 + k + 4);
        bf16x8v bf0 = *(const bf16x8v*)(bB0 + k);
        bf16x8v bf1 = *(const bf16x8v*)(bB1 + k);
        bf16x8v bf2 = *(const bf16x8v*)(bB2 + k);
        bf16x8v bf3 = *(const bf16x8v*)(bB3 + k);
        bf16x8v a0, a1;
#pragma unroll
        for (int i = 0; i < 4; i++) {
            a0[i] = (__bf16)a0lo[i]; a0[4 + i] = (__bf16)a0hi[i];
            a1[i] = (__bf16)a1lo[i]; a1[4 + i] = (__bf16)a1hi[i];
        }
        acc[0][0] = __builtin_amdgcn_mfma_f32_16x16x32_bf16(a0, bf0, acc[0][0], 0, 0, 0);
        acc[0][1] = __builtin_amdgcn_mfma_f32_16x16x32_bf16(a0, bf1, acc[0][1], 0, 0, 0);
        acc[0][2] = __builtin_amdgcn_mfma_f32_16x16x32_bf16(a0, bf2, acc[0][2], 0, 0, 0);
        acc[0][3] = __builtin_amdgcn_mfma_f32_16x16x32_bf16(a0, bf3, acc[0][3], 0, 0, 0);
        acc[1][0] = __builtin_amdgcn_mfma_f32_16x16x32_bf16(a1, bf0, acc[1][0], 0, 0, 0);
        acc[1][1] = __builtin_amdgcn_mfma_f32_16x16x32_bf16(a1, bf1, acc[1][1], 0, 0, 0);
        acc[1][2] = __builtin_amdgcn_mfma_f32_16x16x32_bf16(a1, bf2, acc[1][2], 0, 0, 0);
        acc[1][3] = __builtin_amdgcn_mfma_f32_16x16x32_bf16(a1, bf3, acc[1][3], 0, 0, 0);
    }

    // ---- epilogue: bias + row L2-norm + bf16 store ----
    float ss[2][4];
#pragma unroll
    for (int m = 0; m < 2; m++)
#pragma unroll
        for (int r = 0; r < 4; r++) {
            float s = 0.f;
#pragma unroll
            for (int n = 0; n < 4; n++) {
                float v = acc[m][n][r] + bv[n];
                s += v * v;
            }
            ss[m][r] = s;
        }
#pragma unroll
    for (int off = 1; off < 16; off <<= 1)
#pragma unroll
        for (int m = 0; m < 2; m++)
#pragma unroll
            for (int r = 0; r < 4; r++) ss[m][r] += __shfl_xor(ss[m][r], off, 64);
    if (l15 == 0) {
#pragma unroll
        for (int m = 0; m < 2; m++)
#pragma unroll
            for (int r = 0; r < 4; r++) red[m * 16 + quad * 4 + r][wave] = ss[m][r];
    }
    __syncthreads();
    if (tid < FR) {
        float s = red[tid][0] + red[tid][1] + red[tid][2] + red[tid][3];
        inv_sh[tid] = 1.f / fmaxf(sqrtf(s), 1e-12f);
    }
    __syncthreads();
#pragma unroll
    for (int m = 0; m < 2; m++)
#pragma unroll
        for (int r = 0; r < 4; r++) {
            const int row = m * 16 + quad * 4 + r;
            const float iv = inv_sh[row];
#pragma unroll
            for (int n = 0; n < 4; n++) {
                float v = acc[m][n][r] + bv[n];
                outb[(size_t)(rowBase + row) * DIM + colBase + n * 16 + l15] = (__bf16)(v * iv);
            }
        }
}

// ---------- K2: sim = X@X^T. BK=64 streaming (32 KB LDS -> 3+ blocks/CU),
//              XOR-swizzled staging, shuffle-free unique-writer LDS epilogue, upper-tri grid ----------
#define TILE 128
#define NTILE (NROWS / TILE)              // 64
#define NBLK  (NTILE * (NTILE + 1) / 2)   // 2080

__global__ __launch_bounds__(256, 3) void sim_kernel(
    const __bf16* __restrict__ X,
    float* __restrict__ total,
    float* __restrict__ posv)
{
    __shared__ __align__(16) char smem[32768];
    __bf16* a_base = (__bf16*)smem;            // [2][128][32]
    __bf16* b_base = (__bf16*)(smem + 16384);  // [2][128][32]
    float*  rs     = (float*)smem;             // [128][2][16] = 16 KB
    float*  cs     = (float*)(smem + 16384);   // [128][2][4]  = 4 KB

    const int t = blockIdx.x;
    int bx = (int)((129.0 - sqrt(16641.0 - 8.0 * (double)t)) * 0.5);
    while (64 * (bx + 1) - ((bx + 1) * bx) / 2 <= t) bx++;
    while (64 * bx - (bx * (bx - 1)) / 2 > t) bx--;
    const int by = bx + (t - (64 * bx - (bx * (bx - 1)) / 2));
    const bool diag = (bx == by);

    const int tid  = threadIdx.x;
    const int wave = tid >> 6, lane = tid & 63;
    const int quad = lane >> 4, l15 = lane & 15;
    const int rowBase = bx * TILE;
    const int colBase = by * TILE;
    const int waveRow = (wave >> 1) * 64;
    const int waveCol = (wave & 1) * 64;

    f32x4 acc[4][4];
    const f32x4 zero = {0.f, 0.f, 0.f, 0.f};
#pragma unroll
    for (int m = 0; m < 4; m++)
#pragma unroll
        for (int n = 0; n < 4; n++) acc[m][n] = zero;

    const int r16 = lane >> 2;
    const int b4  = lane & 3;
    const int sw  = (r16 >> 1) & 3;   // stage-side swizzle
    const int sr  = (l15 >> 1) & 3;   // read-side swizzle

    for (int k0 = 0; k0 < DIM; k0 += 64) {
        __syncthreads();
#pragma unroll
        for (int c = 0; c < 2; c++) {
#pragma unroll
            for (int j = 0; j < 2; j++) {
                int rg = wave * 2 + j;   // row-group 0..7
                const __bf16* asrc = X + (size_t)(rowBase + rg * 16 + r16) * DIM + k0 + c * 32 + (b4 ^ sw) * 8;
                const __bf16* bsrc = X + (size_t)(colBase + rg * 16 + r16) * DIM + k0 + c * 32 + (b4 ^ sw) * 8;
                gld_lds16(asrc, a_base + (c * TILE + rg * 16) * 32);
                gld_lds16(bsrc, b_base + (c * TILE + rg * 16) * 32);
            }
        }
        __syncthreads();
#pragma unroll
        for (int ks = 0; ks < 2; ks++) {
            bf16x8v af[4], bfv[4];
#pragma unroll
            for (int m = 0; m < 4; m++)
                af[m] = *(const bf16x8v*)(a_base + (ks * TILE + waveRow + m * 16 + l15) * 32 + (quad ^ sr) * 8);
#pragma unroll
            for (int n = 0; n < 4; n++)
                bfv[n] = *(const bf16x8v*)(b_base + (ks * TILE + waveCol + n * 16 + l15) * 32 + (quad ^ sr) * 8);
#pragma unroll
            for (int m = 0; m < 4; m++)
#pragma unroll
                for (int n = 0; n < 4; n++)
                    acc[m][n] = __builtin_amdgcn_mfma_f32_16x16x32_bf16(af[m], bfv[n], acc[m][n], 0, 0, 0);
        }
    }

    float es[4][4];
    float ecol[4];
#pragma unroll
    for (int n = 0; n < 4; n++) ecol[n] = 0.f;
#pragma unroll
    for (int m = 0; m < 4; m++) {
#pragma unroll
        for (int r = 0; r < 4; r++) {
            int grow = rowBase + waveRow + m * 16 + quad * 4 + r;
            float e_acc = 0.f;
#pragma unroll
            for (int n = 0; n < 4; n++) {
                int gcol = colBase + waveCol + n * 16 + l15;
                float s = acc[m][n][r];
                if (gcol - grow == HALF) { posv[grow] = s; posv[gcol] = s; }
                float e = (gcol == grow) ? 0.f : __expf(s * INV_T);
                e_acc += e;
                ecol[n] += e;
            }
            es[m][r] = e_acc;
        }
    }

    __syncthreads();
    const int wc = wave & 1;
    const int wr = wave >> 1;
#pragma unroll
    for (int m = 0; m < 4; m++)
#pragma unroll
        for (int r = 0; r < 4; r++) {
            int lrow = waveRow + m * 16 + quad * 4 + r;
            rs[(lrow * 2 + wc) * 16 + l15] = es[m][r];
        }
    if (!diag) {
#pragma unroll
        for (int n = 0; n < 4; n++) {
            int lcol = waveCol + n * 16 + l15;
            cs[(lcol * 2 + wr) * 4 + quad] = ecol[n];
        }
    }
    __syncthreads();

    if (tid < TILE) {
        float rsum = 0.f;
#pragma unroll
        for (int i = 0; i < 32; i++) rsum += rs[tid * 32 + i];
        atomicAdd(&total[rowBase + tid], rsum);
        if (!diag) {
            float csum = 0.f;
#pragma unroll
            for (int i = 0; i < 8; i++) csum += cs[tid * 8 + i];
            atomicAdd(&total[colBase + tid], csum);
        }
    }
}

// ---------- K3: loss ----------
__global__ __launch_bounds__(256) void loss_kernel(
    const float* __restrict__ total, const float* __restrict__ posv,
    float* __restrict__ out)
{
    __shared__ float red[4];
    const int tid = threadIdx.x;
    const int i = blockIdx.x * 256 + tid;
    float s = posv[i] * INV_T - __logf(total[i]);
#pragma unroll
    for (int off = 1; off < 64; off <<= 1) s += __shfl_xor(s, off, 64);
    if ((tid & 63) == 0) red[tid >> 6] = s;
    __syncthreads();
    if (tid == 0) {
        float v = red[0] + red[1] + red[2] + red[3];
        atomicAdd(out, -v / (float)NROWS);
    }
}

extern "C" void kernel_launch(void* const* d_in, const int* in_sizes, int n_in,
                              void* d_out, int out_size, void* d_ws, size_t ws_size,
                              hipStream_t stream) {
    const float* emb  = (const float*)d_in[0];
    const float* W    = (const float*)d_in[1];
    const float* bias = (const float*)d_in[2];
    float* out = (float*)d_out;

    char* ws = (char*)d_ws;
    __bf16* outb  = (__bf16*)ws;                          // 4 MB
    __bf16* Wt    = (__bf16*)(ws + (4u << 20));           // 1 MB
    float*  total = (float*)(ws + (5u << 20));            // 32 KB
    float*  posv  = (float*)(ws + (5u << 20) + (32u << 10));

    hipMemsetAsync(total, 0, NROWS * sizeof(float), stream);
    hipMemsetAsync(out, 0, sizeof(float), stream);

    wt_kernel<<<dim3(DIM / 64, EMB / 64), 256, 0, stream>>>(W, Wt);
    gemm_norm_fused<<<dim3(NROWS / FR), 256, 0, stream>>>(emb, Wt, bias, outb);
    sim_kernel<<<dim3(NBLK), 256, 0, stream>>>(outb, total, posv);
    loss_kernel<<<dim3(NROWS / 256), 256, 0, stream>>>(total, posv, out);
}

// Round 6
// 153.374 us; speedup vs baseline: 1.2759x; 1.2759x over previous
//
#include <hip/hip_runtime.h>
#include <math.h>

#define NROWS 8192
#define HALF  4096
#define EMB   2048
#define DIM   256
#define INV_T 10.0f

typedef __bf16 bf16x8v __attribute__((ext_vector_type(8)));
typedef __bf16 bf16x4v __attribute__((ext_vector_type(4)));
typedef float  f32x4   __attribute__((ext_vector_type(4)));

__device__ __forceinline__ void gld_lds16(const void* g, void* l) {
    __builtin_amdgcn_global_load_lds((const __attribute__((address_space(1))) void*)g,
                                     (__attribute__((address_space(3))) void*)l,
                                     16, 0, 0);
}

// ---------- K0: W [2048][256] f32 -> Wt [256][2048] bf16, coalesced tile transpose ----------
__global__ __launch_bounds__(256) void wt_kernel(const float* __restrict__ W,
                                                 __bf16* __restrict__ Wt) {
    __shared__ __bf16 t[64][72];
    const int n0 = blockIdx.x * 64;
    const int k0 = blockIdx.y * 64;
    const int tid = threadIdx.x;
    const int c = tid & 63;
    const int rr = tid >> 6;
#pragma unroll
    for (int it = 0; it < 16; it++) {
        int k = it * 4 + rr;
        t[k][c] = (__bf16)W[(size_t)(k0 + k) * DIM + n0 + c];
    }
    __syncthreads();
#pragma unroll
    for (int it = 0; it < 16; it++) {
        int n = it * 4 + rr;
        Wt[(size_t)(n0 + n) * EMB + k0 + c] = t[c][n];
    }
}

// ---------- K1a: head GEMM. v6: SMALL TILES FOR CROSS-BLOCK LATENCY HIDING. ----------
// 32 rows x 64 cols x K=2048, grid (256,4) = 1024 blocks, 12 KB LDS,
// launch_bounds(256,4) -> 4+ blocks/CU resident. One block's barrier/vmcnt
// drain hides under co-resident blocks' compute (the 42-46us plateau of all
// 256-block variants was ONE resident block = fully exposed per-iter latency).
// A: reg-staged f32->bf16 with write-side granule-XOR swizzle.
// B: gld_lds16 with pre-swizzled per-lane SOURCE (linear LDS dest), read-side
//    applies the same XOR -> conflict-free ds_read_b128.
// Emits out8 = A@W + bias in f32 (same K-accumulation chain as before).
#define GBM 32
#define GBN 64
#define GBK 64

__global__ __launch_bounds__(256, 4) void head_gemm(
    const float* __restrict__ A,      // [8192][2048] f32
    const __bf16* __restrict__ Wt,    // [256][2048] bf16
    const float* __restrict__ bias,   // [256] f32
    float* __restrict__ out8)         // [8192][256] f32 head+bias
{
    __shared__ __bf16 a_sh[GBM][GBK];   // 4 KB
    __shared__ __bf16 b_sh[GBN][GBK];   // 8 KB

    const int tid  = threadIdx.x;
    const int wave = tid >> 6, lane = tid & 63;
    const int quad = lane >> 4, l15 = lane & 15;
    const int rowBase = blockIdx.x * GBM;
    const int colBase = blockIdx.y * GBN;
    const int wr = wave >> 1;   // 0..1: 16-row half
    const int wc = wave & 1;    // 0..1: 32-col half

    // A staging: thread -> row tid>>3 (0..31), granule tid&7 (8 bf16 = 16B)
    const int ar = tid >> 3, ag = tid & 7;
    const float* aPtr = A + (size_t)(rowBase + ar) * EMB + ag * 8;
    __bf16* aDst = &a_sh[ar][(ag ^ (ar & 7)) * 8];

    // B staging: wave stages chunks {wave*2, wave*2+1}; chunk = 8 cols = 1KB.
    // lane l -> dest byte l*16 -> col chunk*8 + (l>>3), granule l&7.
    // source granule pre-swizzled: g ^ (col&7).
    size_t bSrcOff[2];
    __bf16* bDst[2];
#pragma unroll
    for (int j = 0; j < 2; j++) {
        const int chunk = wave * 2 + j;
        const int c = chunk * 8 + (lane >> 3);
        const int g = lane & 7;
        bSrcOff[j] = (size_t)(colBase + c) * EMB + (g ^ (c & 7)) * 8;
        bDst[j]    = &b_sh[0][0] + chunk * 512;   // 512 bf16 = 1KB
    }

    f32x4 acc[2];
    const f32x4 zero = {0.f, 0.f, 0.f, 0.f};
    acc[0] = zero; acc[1] = zero;

    float bv[2];
#pragma unroll
    for (int n = 0; n < 2; n++) bv[n] = bias[colBase + wc * 32 + n * 16 + l15];

    for (int kk = 0; kk < EMB; kk += GBK) {
        __syncthreads();
        // stage A (reg roundtrip for f32->bf16)
        f32x4 lo = *(const f32x4*)(aPtr + kk);
        f32x4 hi = *(const f32x4*)(aPtr + kk + 4);
        // stage B (async direct to LDS, source-swizzled)
        gld_lds16(Wt + bSrcOff[0] + kk, bDst[0]);
        gld_lds16(Wt + bSrcOff[1] + kk, bDst[1]);
        bf16x8v av;
#pragma unroll
        for (int i = 0; i < 4; i++) { av[i] = (__bf16)lo[i]; av[4 + i] = (__bf16)hi[i]; }
        *(bf16x8v*)aDst = av;
        __syncthreads();
        // compute
#pragma unroll
        for (int ks = 0; ks < 2; ks++) {
            const int arow = wr * 16 + l15;
            bf16x8v af = *(const bf16x8v*)&a_sh[arow][(((ks * 4 + quad) ^ (arow & 7)) * 8)];
#pragma unroll
            for (int n = 0; n < 2; n++) {
                const int col = wc * 32 + n * 16 + l15;
                bf16x8v bf = *(const bf16x8v*)&b_sh[col][(((ks * 4 + quad) ^ (col & 7)) * 8)];
                acc[n] = __builtin_amdgcn_mfma_f32_16x16x32_bf16(af, bf, acc[n], 0, 0, 0);
            }
        }
    }

    // epilogue: + bias, f32 store
#pragma unroll
    for (int n = 0; n < 2; n++)
#pragma unroll
        for (int r = 0; r < 4; r++) {
            const int grow = rowBase + wr * 16 + quad * 4 + r;
            const int gcol = colBase + wc * 32 + n * 16 + l15;
            out8[(size_t)grow * DIM + gcol] = acc[n][r] + bv[n];
        }
}

// ---------- K1b: L2-normalize rows of out8, emit bf16 X ----------
__global__ __launch_bounds__(256) void norm2_kernel(
    const float* __restrict__ out8,
    __bf16* __restrict__ outb)
{
    const int tid  = threadIdx.x;
    const int wave = tid >> 6, lane = tid & 63;
    const int row  = blockIdx.x * 4 + wave;

    float4 v = *(const float4*)(out8 + (size_t)row * DIM + lane * 4);
    float ss = v.x * v.x + v.y * v.y + v.z * v.z + v.w * v.w;
#pragma unroll
    for (int off = 1; off < 64; off <<= 1) ss += __shfl_xor(ss, off, 64);
    float inv = 1.f / fmaxf(sqrtf(ss), 1e-12f);

    bf16x4v o;
    o[0] = (__bf16)(v.x * inv); o[1] = (__bf16)(v.y * inv);
    o[2] = (__bf16)(v.z * inv); o[3] = (__bf16)(v.w * inv);
    *(bf16x4v*)(outb + (size_t)row * DIM + lane * 4) = o;
}

// ---------- K2: sim = X@X^T. BK=64 streaming (32 KB LDS -> 3+ blocks/CU),
//              XOR-swizzled staging, shuffle-free unique-writer LDS epilogue, upper-tri grid ----------
#define TILE 128
#define NTILE (NROWS / TILE)              // 64
#define NBLK  (NTILE * (NTILE + 1) / 2)   // 2080

__global__ __launch_bounds__(256, 3) void sim_kernel(
    const __bf16* __restrict__ X,
    float* __restrict__ total,
    float* __restrict__ posv)
{
    __shared__ __align__(16) char smem[32768];
    __bf16* a_base = (__bf16*)smem;            // [2][128][32]
    __bf16* b_base = (__bf16*)(smem + 16384);  // [2][128][32]
    float*  rs     = (float*)smem;             // [128][2][16] = 16 KB
    float*  cs     = (float*)(smem + 16384);   // [128][2][4]  = 4 KB

    const int t = blockIdx.x;
    int bx = (int)((129.0 - sqrt(16641.0 - 8.0 * (double)t)) * 0.5);
    while (64 * (bx + 1) - ((bx + 1) * bx) / 2 <= t) bx++;
    while (64 * bx - (bx * (bx - 1)) / 2 > t) bx--;
    const int by = bx + (t - (64 * bx - (bx * (bx - 1)) / 2));
    const bool diag = (bx == by);

    const int tid  = threadIdx.x;
    const int wave = tid >> 6, lane = tid & 63;
    const int quad = lane >> 4, l15 = lane & 15;
    const int rowBase = bx * TILE;
    const int colBase = by * TILE;
    const int waveRow = (wave >> 1) * 64;
    const int waveCol = (wave & 1) * 64;

    f32x4 acc[4][4];
    const f32x4 zero = {0.f, 0.f, 0.f, 0.f};
#pragma unroll
    for (int m = 0; m < 4; m++)
#pragma unroll
        for (int n = 0; n < 4; n++) acc[m][n] = zero;

    const int r16 = lane >> 2;
    const int b4  = lane & 3;
    const int sw  = (r16 >> 1) & 3;   // stage-side swizzle
    const int sr  = (l15 >> 1) & 3;   // read-side swizzle

    for (int k0 = 0; k0 < DIM; k0 += 64) {
        __syncthreads();
#pragma unroll
        for (int c = 0; c < 2; c++) {
#pragma unroll
            for (int j = 0; j < 2; j++) {
                int rg = wave * 2 + j;   // row-group 0..7
                const __bf16* asrc = X + (size_t)(rowBase + rg * 16 + r16) * DIM + k0 + c * 32 + (b4 ^ sw) * 8;
                const __bf16* bsrc = X + (size_t)(colBase + rg * 16 + r16) * DIM + k0 + c * 32 + (b4 ^ sw) * 8;
                gld_lds16(asrc, a_base + (c * TILE + rg * 16) * 32);
                gld_lds16(bsrc, b_base + (c * TILE + rg * 16) * 32);
            }
        }
        __syncthreads();
#pragma unroll
        for (int ks = 0; ks < 2; ks++) {
            bf16x8v af[4], bfv[4];
#pragma unroll
            for (int m = 0; m < 4; m++)
                af[m] = *(const bf16x8v*)(a_base + (ks * TILE + waveRow + m * 16 + l15) * 32 + (quad ^ sr) * 8);
#pragma unroll
            for (int n = 0; n < 4; n++)
                bfv[n] = *(const bf16x8v*)(b_base + (ks * TILE + waveCol + n * 16 + l15) * 32 + (quad ^ sr) * 8);
#pragma unroll
            for (int m = 0; m < 4; m++)
#pragma unroll
                for (int n = 0; n < 4; n++)
                    acc[m][n] = __builtin_amdgcn_mfma_f32_16x16x32_bf16(af[m], bfv[n], acc[m][n], 0, 0, 0);
        }
    }

    float es[4][4];
    float ecol[4];
#pragma unroll
    for (int n = 0; n < 4; n++) ecol[n] = 0.f;
#pragma unroll
    for (int m = 0; m < 4; m++) {
#pragma unroll
        for (int r = 0; r < 4; r++) {
            int grow = rowBase + waveRow + m * 16 + quad * 4 + r;
            float e_acc = 0.f;
#pragma unroll
            for (int n = 0; n < 4; n++) {
                int gcol = colBase + waveCol + n * 16 + l15;
                float s = acc[m][n][r];
                if (gcol - grow == HALF) { posv[grow] = s; posv[gcol] = s; }
                float e = (gcol == grow) ? 0.f : __expf(s * INV_T);
                e_acc += e;
                ecol[n] += e;
            }
            es[m][r] = e_acc;
        }
    }

    __syncthreads();
    const int wc = wave & 1;
    const int wr = wave >> 1;
#pragma unroll
    for (int m = 0; m < 4; m++)
#pragma unroll
        for (int r = 0; r < 4; r++) {
            int lrow = waveRow + m * 16 + quad * 4 + r;
            rs[(lrow * 2 + wc) * 16 + l15] = es[m][r];
        }
    if (!diag) {
#pragma unroll
        for (int n = 0; n < 4; n++) {
            int lcol = waveCol + n * 16 + l15;
            cs[(lcol * 2 + wr) * 4 + quad] = ecol[n];
        }
    }
    __syncthreads();

    if (tid < TILE) {
        float rsum = 0.f;
#pragma unroll
        for (int i = 0; i < 32; i++) rsum += rs[tid * 32 + i];
        atomicAdd(&total[rowBase + tid], rsum);
        if (!diag) {
            float csum = 0.f;
#pragma unroll
            for (int i = 0; i < 8; i++) csum += cs[tid * 8 + i];
            atomicAdd(&total[colBase + tid], csum);
        }
    }
}

// ---------- K3: loss ----------
__global__ __launch_bounds__(256) void loss_kernel(
    const float* __restrict__ total, const float* __restrict__ posv,
    float* __restrict__ out)
{
    __shared__ float red[4];
    const int tid = threadIdx.x;
    const int i = blockIdx.x * 256 + tid;
    float s = posv[i] * INV_T - __logf(total[i]);
#pragma unroll
    for (int off = 1; off < 64; off <<= 1) s += __shfl_xor(s, off, 64);
    if ((tid & 63) == 0) red[tid >> 6] = s;
    __syncthreads();
    if (tid == 0) {
        float v = red[0] + red[1] + red[2] + red[3];
        atomicAdd(out, -v / (float)NROWS);
    }
}

extern "C" void kernel_launch(void* const* d_in, const int* in_sizes, int n_in,
                              void* d_out, int out_size, void* d_ws, size_t ws_size,
                              hipStream_t stream) {
    const float* emb  = (const float*)d_in[0];
    const float* W    = (const float*)d_in[1];
    const float* bias = (const float*)d_in[2];
    float* out = (float*)d_out;

    char* ws = (char*)d_ws;
    float*  out8  = (float*)ws;                           // 8 MB
    __bf16* outb  = (__bf16*)(ws + (8u << 20));           // 4 MB
    __bf16* Wt    = (__bf16*)(ws + (12u << 20));          // 1 MB
    float*  total = (float*)(ws + (13u << 20));           // 32 KB
    float*  posv  = (float*)(ws + (13u << 20) + (32u << 10));

    hipMemsetAsync(total, 0, NROWS * sizeof(float), stream);
    hipMemsetAsync(out, 0, sizeof(float), stream);

    wt_kernel<<<dim3(DIM / 64, EMB / 64), 256, 0, stream>>>(W, Wt);
    head_gemm<<<dim3(NROWS / GBM, DIM / GBN), 256, 0, stream>>>(emb, Wt, bias, out8);
    norm2_kernel<<<dim3(NROWS / 4), 256, 0, stream>>>(out8, outb);
    sim_kernel<<<dim3(NBLK), 256, 0, stream>>>(outb, total, posv);
    loss_kernel<<<dim3(NROWS / 256), 256, 0, stream>>>(total, posv, out);
}